// Round 7
// baseline (1084.988 us; speedup 1.0000x reference)
//
#include <hip/hip_runtime.h>
#include <hip/hip_bf16.h>
#include <math.h>

#define BS   8
#define NP   4096
#define NC   1024
#define KN   32
#define CIN  128
#define CMID 183
#define COUT 256
#define BN_EPS 1e-5f

// ---- workspace layout (bytes) ----
#define OFF_SQ   0                    // BS*NP floats            = 131072
#define OFF_FPS  131072               // BS*NC ints              = 32768
#define OFF_GRP  163840               // BS*NC*KN ints           = 1048576 -> ends 1212416
#define OFF_A1   1212416              // 192 floats (pad 1K)
#define OFF_B1   1213440
#define OFF_A2   1214464              // 256 floats
#define OFF_B2   1215488
#define OFF_W1F  1216512              // 30720 u16 = 61440 B  (B-frag packed, 192x160)
#define OFF_W2F  1277952              // 49152 u16 = 98304 B  (B-frag packed, 256x192)
// total 1376256 bytes

typedef float  f32x4 __attribute__((ext_vector_type(4)));
typedef short  s16x8 __attribute__((ext_vector_type(8)));
typedef unsigned short u16;
typedef u16    u16x8 __attribute__((ext_vector_type(8)));
typedef unsigned long long u64;
typedef unsigned int u32;

static __device__ __forceinline__ u16 f2bf(float f) {
  __hip_bfloat16 h = __float2bfloat16(f);   // RNE
  return __builtin_bit_cast(u16, h);
}

// ============================================================ prep
__global__ __launch_bounds__(256) void prep_kernel(
    const float* __restrict__ xyz,
    const float* __restrict__ W1, const float* __restrict__ W2,
    const float* __restrict__ b1, const float* __restrict__ g1, const float* __restrict__ be1,
    const float* __restrict__ m1, const float* __restrict__ v1,
    const float* __restrict__ b2, const float* __restrict__ g2, const float* __restrict__ be2,
    const float* __restrict__ m2, const float* __restrict__ v2,
    float* __restrict__ sq, float* __restrict__ A1, float* __restrict__ B1,
    float* __restrict__ A2, float* __restrict__ B2,
    u16* __restrict__ W1f, u16* __restrict__ W2f) {
  int i = blockIdx.x * 256 + threadIdx.x;
  if (i < BS * NP) {
    #pragma clang fp contract(off)
    float x = xyz[i*3+0], y = xyz[i*3+1], z = xyz[i*3+2];
    sq[i] = (x*x + y*y) + z*z;
  }
  if (i < 192) {
    float a = 0.f, bb = 0.f;
    if (i < CMID) { a = g1[i] / sqrtf(v1[i] + BN_EPS); bb = fmaf(b1[i] - m1[i], a, be1[i]); }
    A1[i] = a; B1[i] = bb;
  }
  if (i < COUT) { float a = g2[i] / sqrtf(v2[i] + BN_EPS); A2[i] = a; B2[i] = fmaf(b2[i] - m2[i], a, be2[i]); }
  if (i < 30720) {               // W1f: 12 N-tiles x 5 K-tiles
    int j = i & 7, lane = (i >> 3) & 63, r = i >> 9;
    int kt = r % 5, nt = r / 5;
    int n = nt*16 + (lane & 15);
    int k = kt*32 + ((lane >> 4) << 3) + j;
    W1f[i] = (n < CMID && k < 131) ? f2bf(W1[n*131 + k]) : (u16)0;
  }
  if (i < 49152) {               // W2f: 16 N-tiles x 6 K-tiles
    int j = i & 7, lane = (i >> 3) & 63, r = i >> 9;
    int kt = r % 6, nt = r / 6;
    int n = nt*16 + (lane & 15);
    int k = kt*32 + ((lane >> 4) << 3) + j;
    W2f[i] = (k < CMID) ? f2bf(W2[n*CMID + k]) : (u16)0;
  }
}

// ============================================================ FPS v6
// No wave butterfly at all. Per thread: scalar update (byte-identical to v4)
// + float/idx local tree (strict > on ascending scan => lowest index at ties),
// then ONE LDS atomicMax of the unique u64 key (distbits<<32 | ~idx) into a
// per-wave slot (ds_max_u64; 8 slots). Single barrier; 4-deep slot rotation
// makes the zeroing race-free (reads of slot s at iter i vs re-zero at iter
// i+2 are separated by barrier i+1). Post-barrier: 8-slot broadcast combine.
// Selection semantics identical to v4 (max dist, tie -> lowest index).
#define FPS_T 512

static __device__ __forceinline__ u64 kmax(u64 a, u64 b) { return a > b ? a : b; }

__global__ __launch_bounds__(FPS_T) void fps_kernel(
    const float* __restrict__ xyz,
    int* __restrict__ fps_idx, float* __restrict__ center_out) {
  #pragma clang fp contract(off)
  int b = blockIdx.x, t = threadIdx.x;
  const float* p = xyz + (size_t)b * NP * 3;
  __shared__ __align__(16) float s_xyz[NP][4];   // 64 KB, 16B rows for b128 broadcast
  __shared__ u64 s_best[4][8];                   // [rotation][wave]
  for (int i = t; i < NP; i += FPS_T) {
    s_xyz[i][0] = p[i*3+0]; s_xyz[i][1] = p[i*3+1];
    s_xyz[i][2] = p[i*3+2]; s_xyz[i][3] = 0.f;
  }
  if (t < 32) ((u64*)s_best)[t] = 0ull;
  __syncthreads();
  const int PPT = NP / FPS_T;             // 8 points/thread
  int base = t * PPT;
  float px[PPT], py[PPT], pz[PPT], dist[PPT];
  #pragma unroll
  for (int j = 0; j < PPT; ++j) {
    px[j] = s_xyz[base+j][0]; py[j] = s_xyz[base+j][1]; pz[j] = s_xyz[base+j][2];
    dist[j] = INFINITY;
  }
  int w = t >> 6;
  u32 far = 0;
  float cx = s_xyz[0][0], cy = s_xyz[0][1], cz = s_xyz[0][2];
  for (int it = 0; it < NC; ++it) {
    if (t == 0) {
      fps_idx[b*NC + it] = (int)far;
      center_out[(size_t)(b*NC + it)*3 + 0] = cx;
      center_out[(size_t)(b*NC + it)*3 + 1] = cy;
      center_out[(size_t)(b*NC + it)*3 + 2] = cz;
    }
    // ---- scalar update (exact order: (dx*dx + dy*dy) + dz*dz, no fma)
    //      + float/idx tree: strict >, ascending j => tie keeps lowest index
    float bd = -1.0f; int bi = 0;
    #pragma unroll
    for (int j = 0; j < PPT; ++j) {
      float dx = px[j] - cx, dy = py[j] - cy, dz = pz[j] - cz;
      float d = (dx*dx + dy*dy) + dz*dz;
      float nd = fminf(dist[j], d);
      dist[j] = nd;
      bool bt = nd > bd;
      bd = bt ? nd : bd;
      bi = bt ? (base + j) : bi;
    }
    // ---- one atomic per thread into this wave's slot (dist>=0 => bits monotonic)
    u64 key = ((u64)__builtin_bit_cast(u32, bd) << 32) | (u32)~(u32)bi;
    int par = it & 3;
    atomicMax(&s_best[par][w], key);
    if (t < 8) s_best[(it + 2) & 3][t] = 0ull;   // prep slots for iter it+2
    __syncthreads();
    // ---- combine 8 wave slots (broadcast reads, 3-level tree)
    u64 q0 = kmax(s_best[par][0], s_best[par][1]);
    u64 q1 = kmax(s_best[par][2], s_best[par][3]);
    u64 q2 = kmax(s_best[par][4], s_best[par][5]);
    u64 q3 = kmax(s_best[par][6], s_best[par][7]);
    u64 best = kmax(kmax(q0, q1), kmax(q2, q3));
    far = ~(u32)best;
    f32x4 c4 = *(const f32x4*)&s_xyz[far][0];   // aligned broadcast ds_read_b128
    cx = c4.x; cy = c4.y; cz = c4.z;
  }
}

// ============================================================ kNN (unchanged)
__global__ __launch_bounds__(256) void knn_kernel(
    const float* __restrict__ xyz, const float* __restrict__ sq,
    const int* __restrict__ fps_idx, int* __restrict__ grp) {
  #pragma clang fp contract(off)
  int L = blockIdx.x;
  int b = L & 7, ci = L >> 3;
  int t = threadIdx.x;
  const float* p   = xyz + (size_t)b * NP * 3;
  const float* sqb = sq + b * NP;
  __shared__ float s_d[NP];
  __shared__ float s_pval[2][4];
  __shared__ int   s_pidx[2][4];
  int center = fps_idx[b*NC + ci];
  float cx = p[center*3+0], cy = p[center*3+1], cz = p[center*3+2];
  float sqi = sqb[center];
  const int PPT = NP / 256;
  #pragma unroll
  for (int k = 0; k < PPT; ++k) {
    int j = t + k * 256;
    float dot = (cx*p[j*3+0] + cy*p[j*3+1]) + cz*p[j*3+2];
    s_d[j] = (sqi - 2.0f*dot) + sqb[j];
  }
  __syncthreads();
  int base = t * PPT;
  float lv = INFINITY; int li = 0x7fffffff;
  #pragma unroll
  for (int j = 0; j < PPT; ++j) {
    float v = s_d[base + j];
    bool bt = v < lv;
    lv = bt ? v : lv; li = bt ? (base + j) : li;
  }
  int lane = t & 63, wave = t >> 6;
  int myidx = 0;
  for (int it = 0; it < KN; ++it) {
    float bv = lv; int bi = li;
    #pragma unroll
    for (int off = 1; off < 64; off <<= 1) {
      float ov = __shfl_xor(bv, off);
      int   oi = __shfl_xor(bi, off);
      bool take = (ov < bv) || (ov == bv && oi < bi);
      bv = take ? ov : bv; bi = take ? oi : bi;
    }
    int par = it & 1;
    if (lane == 0) { s_pval[par][wave] = bv; s_pidx[par][wave] = bi; }
    __syncthreads();
    bv = s_pval[par][0]; bi = s_pidx[par][0];
    #pragma unroll
    for (int w = 1; w < 4; ++w) {
      float ov = s_pval[par][w]; int oi = s_pidx[par][w];
      bool take = (ov < bv) || (ov == bv && oi < bi);
      bv = take ? ov : bv; bi = take ? oi : bi;
    }
    if (t == it) myidx = bi;
    if ((bi >> 4) == t) {
      s_d[bi] = INFINITY;
      lv = INFINITY; li = 0x7fffffff;
      #pragma unroll
      for (int j = 0; j < PPT; ++j) {
        float v = s_d[base + j];
        bool bt = v < lv;
        lv = bt ? v : lv; li = bt ? (base + j) : li;
      }
    }
  }
  if (t < KN) grp[((size_t)(b*NC + ci))*KN + t] = myidx;
}

// ============================================================ fused MLP + maxpool (MFMA bf16, unchanged)
__global__ __launch_bounds__(256) void mlp_kernel(
    const float* __restrict__ xyz, const float* __restrict__ fea,
    const u16* __restrict__ W1f, const u16* __restrict__ W2f,
    const float* __restrict__ A1, const float* __restrict__ B1,
    const float* __restrict__ A2, const float* __restrict__ B2,
    const int* __restrict__ grp, const float* __restrict__ center_xyz,
    float* __restrict__ new_fea) {
  int L = blockIdx.x;
  int b = L & 7, pi = L >> 3;
  size_t gbase = (size_t)b * NC + pi * 2;
  int t = threadIdx.x;
  int lane = t & 63, w = t >> 6;

  __shared__ u16 sx[64][168];
  __shared__ u16 sy1[64][200];
  __shared__ int s_gidx[64];
  __shared__ float s_c[2][3];

  if (t < 64) s_gidx[t] = grp[(gbase + (t >> 5)) * KN + (t & 31)];
  if (t < 6)  s_c[t/3][t%3] = center_xyz[(gbase + t/3)*3 + (t%3)];
  __syncthreads();

  {
    int r = t >> 2, q0 = (t & 3) * 32;
    const float* src = fea + ((size_t)b*NP + s_gidx[r])*CIN + q0;
    #pragma unroll
    for (int j = 0; j < 32; j += 8) {
      float4 v0 = *(const float4*)(src + j);
      float4 v1 = *(const float4*)(src + j + 4);
      u16x8 pk;
      pk[0]=f2bf(v0.x); pk[1]=f2bf(v0.y); pk[2]=f2bf(v0.z); pk[3]=f2bf(v0.w);
      pk[4]=f2bf(v1.x); pk[5]=f2bf(v1.y); pk[6]=f2bf(v1.z); pk[7]=f2bf(v1.w);
      *(u16x8*)&sx[r][q0 + j] = pk;
    }
  }
  if (t < 64) {
    int c = t >> 5;
    const float* g = xyz + ((size_t)b*NP + s_gidx[t])*3;
    sx[t][128] = f2bf(g[0] - s_c[c][0]);
    sx[t][129] = f2bf(g[1] - s_c[c][1]);
    sx[t][130] = f2bf(g[2] - s_c[c][2]);
    #pragma unroll
    for (int j = 131; j < 160; ++j) sx[t][j] = 0;
  }
  __syncthreads();

  const f32x4 zero = {0.f, 0.f, 0.f, 0.f};

  // ---- layer 1
  {
    f32x4 acc[4][3];
    #pragma unroll
    for (int mt = 0; mt < 4; ++mt)
      #pragma unroll
      for (int nt = 0; nt < 3; ++nt) acc[mt][nt] = zero;
    #pragma unroll
    for (int kt = 0; kt < 5; ++kt) {
      s16x8 a[4];
      #pragma unroll
      for (int mt = 0; mt < 4; ++mt)
        a[mt] = *(const s16x8*)&sx[mt*16 + (lane & 15)][kt*32 + ((lane >> 4) << 3)];
      s16x8 bf[3];
      #pragma unroll
      for (int nt = 0; nt < 3; ++nt)
        bf[nt] = *(const s16x8*)&W1f[(((w*3 + nt)*5 + kt)*64 + lane) * 8];
      #pragma unroll
      for (int mt = 0; mt < 4; ++mt)
        #pragma unroll
        for (int nt = 0; nt < 3; ++nt)
          acc[mt][nt] = __builtin_amdgcn_mfma_f32_16x16x32_bf16(a[mt], bf[nt], acc[mt][nt], 0, 0, 0);
    }
    #pragma unroll
    for (int nt = 0; nt < 3; ++nt) {
      int c = w*48 + nt*16 + (lane & 15);
      float av = A1[c], bv = B1[c];
      #pragma unroll
      for (int mt = 0; mt < 4; ++mt) {
        #pragma unroll
        for (int r = 0; r < 4; ++r) {
          float v = fmaxf(fmaf(acc[mt][nt][r], av, bv), 0.f);
          sy1[mt*16 + ((lane >> 4) << 2) + r][c] = f2bf(v);
        }
      }
    }
  }
  __syncthreads();

  // ---- layer 2 + BN/ReLU + maxpool
  {
    f32x4 acc[4][4];
    #pragma unroll
    for (int mt = 0; mt < 4; ++mt)
      #pragma unroll
      for (int nt = 0; nt < 4; ++nt) acc[mt][nt] = zero;
    #pragma unroll
    for (int kt = 0; kt < 6; ++kt) {
      s16x8 a[4];
      #pragma unroll
      for (int mt = 0; mt < 4; ++mt)
        a[mt] = *(const s16x8*)&sy1[mt*16 + (lane & 15)][kt*32 + ((lane >> 4) << 3)];
      s16x8 bf[4];
      #pragma unroll
      for (int nt = 0; nt < 4; ++nt)
        bf[nt] = *(const s16x8*)&W2f[(((w*4 + nt)*6 + kt)*64 + lane) * 8];
      #pragma unroll
      for (int mt = 0; mt < 4; ++mt)
        #pragma unroll
        for (int nt = 0; nt < 4; ++nt)
          acc[mt][nt] = __builtin_amdgcn_mfma_f32_16x16x32_bf16(a[mt], bf[nt], acc[mt][nt], 0, 0, 0);
    }
    #pragma unroll
    for (int nt = 0; nt < 4; ++nt) {
      int c = w*64 + nt*16 + (lane & 15);
      float av = A2[c], bv = B2[c];
      float c0 = 0.f, c1 = 0.f;
      #pragma unroll
      for (int mt = 0; mt < 2; ++mt)
        #pragma unroll
        for (int r = 0; r < 4; ++r)
          c0 = fmaxf(c0, fmaf(acc[mt][nt][r], av, bv));
      #pragma unroll
      for (int mt = 2; mt < 4; ++mt)
        #pragma unroll
        for (int r = 0; r < 4; ++r)
          c1 = fmaxf(c1, fmaf(acc[mt][nt][r], av, bv));
      c0 = fmaxf(c0, __shfl_xor(c0, 16)); c0 = fmaxf(c0, __shfl_xor(c0, 32));
      c1 = fmaxf(c1, __shfl_xor(c1, 16)); c1 = fmaxf(c1, __shfl_xor(c1, 32));
      if (lane < 16)      new_fea[gbase*COUT + c] = c0;
      else if (lane < 32) new_fea[(gbase + 1)*COUT + c] = c1;
    }
  }
}

// ============================================================ launch
extern "C" void kernel_launch(void* const* d_in, const int* in_sizes, int n_in,
                              void* d_out, int out_size, void* d_ws, size_t ws_size,
                              hipStream_t stream) {
  const float* xyz = (const float*)d_in[0];
  const float* fea = (const float*)d_in[1];
  const float* W1  = (const float*)d_in[2];
  const float* b1  = (const float*)d_in[3];
  const float* g1  = (const float*)d_in[4];
  const float* be1 = (const float*)d_in[5];
  const float* m1  = (const float*)d_in[6];
  const float* v1  = (const float*)d_in[7];
  const float* W2  = (const float*)d_in[8];
  const float* b2  = (const float*)d_in[9];
  const float* g2  = (const float*)d_in[10];
  const float* be2 = (const float*)d_in[11];
  const float* m2  = (const float*)d_in[12];
  const float* v2  = (const float*)d_in[13];

  char* ws = (char*)d_ws;
  float* sq   = (float*)(ws + OFF_SQ);
  int*   fpsi = (int*)  (ws + OFF_FPS);
  int*   grp  = (int*)  (ws + OFF_GRP);
  float* A1   = (float*)(ws + OFF_A1);
  float* B1   = (float*)(ws + OFF_B1);
  float* A2   = (float*)(ws + OFF_A2);
  float* B2   = (float*)(ws + OFF_B2);
  u16*   W1f  = (u16*)  (ws + OFF_W1F);
  u16*   W2f  = (u16*)  (ws + OFF_W2F);

  float* out        = (float*)d_out;
  float* center_out = out;                   // [BS][NC][3]
  float* new_fea    = out + (size_t)BS*NC*3; // [BS][NC][COUT]

  prep_kernel<<<192, 256, 0, stream>>>(xyz, W1, W2, b1,g1,be1,m1,v1, b2,g2,be2,m2,v2,
                                       sq, A1,B1,A2,B2, W1f, W2f);
  fps_kernel<<<BS, FPS_T, 0, stream>>>(xyz, fpsi, center_out);
  knn_kernel<<<BS*NC, 256, 0, stream>>>(xyz, sq, fpsi, grp);
  mlp_kernel<<<BS*NC/2, 256, 0, stream>>>(xyz, fea, W1f, W2f, A1,B1,A2,B2,
                                          grp, center_out, new_fea);
}

// Round 8
// 996.223 us; speedup vs baseline: 1.0891x; 1.0891x over previous
//
#include <hip/hip_runtime.h>
#include <hip/hip_bf16.h>
#include <math.h>

#define BS   8
#define NP   4096
#define NC   1024
#define KN   32
#define CIN  128
#define CMID 183
#define COUT 256
#define BN_EPS 1e-5f

// ---- workspace layout (bytes) ----
#define OFF_SQ   0                    // BS*NP floats            = 131072
#define OFF_FPS  131072               // BS*NC ints              = 32768
#define OFF_GRP  163840               // BS*NC*KN ints           = 1048576 -> ends 1212416
#define OFF_A1   1212416              // 192 floats (pad 1K)
#define OFF_B1   1213440
#define OFF_A2   1214464              // 256 floats
#define OFF_B2   1215488
#define OFF_W1F  1216512              // 30720 u16 = 61440 B  (B-frag packed, 192x160)
#define OFF_W2F  1277952              // 49152 u16 = 98304 B  (B-frag packed, 256x192)
// total 1376256 bytes

typedef float  f32x4 __attribute__((ext_vector_type(4)));
typedef short  s16x8 __attribute__((ext_vector_type(8)));
typedef unsigned short u16;
typedef u16    u16x8 __attribute__((ext_vector_type(8)));
typedef unsigned long long u64;
typedef unsigned int u32;

static __device__ __forceinline__ u16 f2bf(float f) {
  __hip_bfloat16 h = __float2bfloat16(f);   // RNE
  return __builtin_bit_cast(u16, h);
}

// ============================================================ prep
__global__ __launch_bounds__(256) void prep_kernel(
    const float* __restrict__ xyz,
    const float* __restrict__ W1, const float* __restrict__ W2,
    const float* __restrict__ b1, const float* __restrict__ g1, const float* __restrict__ be1,
    const float* __restrict__ m1, const float* __restrict__ v1,
    const float* __restrict__ b2, const float* __restrict__ g2, const float* __restrict__ be2,
    const float* __restrict__ m2, const float* __restrict__ v2,
    float* __restrict__ sq, float* __restrict__ A1, float* __restrict__ B1,
    float* __restrict__ A2, float* __restrict__ B2,
    u16* __restrict__ W1f, u16* __restrict__ W2f) {
  int i = blockIdx.x * 256 + threadIdx.x;
  if (i < BS * NP) {
    #pragma clang fp contract(off)
    float x = xyz[i*3+0], y = xyz[i*3+1], z = xyz[i*3+2];
    sq[i] = (x*x + y*y) + z*z;
  }
  if (i < 192) {
    float a = 0.f, bb = 0.f;
    if (i < CMID) { a = g1[i] / sqrtf(v1[i] + BN_EPS); bb = fmaf(b1[i] - m1[i], a, be1[i]); }
    A1[i] = a; B1[i] = bb;
  }
  if (i < COUT) { float a = g2[i] / sqrtf(v2[i] + BN_EPS); A2[i] = a; B2[i] = fmaf(b2[i] - m2[i], a, be2[i]); }
  if (i < 30720) {               // W1f: 12 N-tiles x 5 K-tiles
    int j = i & 7, lane = (i >> 3) & 63, r = i >> 9;
    int kt = r % 5, nt = r / 5;
    int n = nt*16 + (lane & 15);
    int k = kt*32 + ((lane >> 4) << 3) + j;
    W1f[i] = (n < CMID && k < 131) ? f2bf(W1[n*131 + k]) : (u16)0;
  }
  if (i < 49152) {               // W2f: 16 N-tiles x 6 K-tiles
    int j = i & 7, lane = (i >> 3) & 63, r = i >> 9;
    int kt = r % 6, nt = r / 6;
    int n = nt*16 + (lane & 15);
    int k = kt*32 + ((lane >> 4) << 3) + j;
    W2f[i] = (k < CMID) ? f2bf(W2[n*CMID + k]) : (u16)0;
  }
}

// ============================================================ FPS v7 (DPP bisect)
// = v4 (passing: scalar update, u64 keys, local tree, parity LDS partials,
//   8-slot combine, aligned b128 center fetch) with ONE delta:
//   the 6-stage shfl_xor butterfly + ballot/ffs winner-pick is replaced by a
//   u64-carrying butterfly whose stages 1/2/4/8 are DPP (quad_perm 0xB1/0x4E,
//   row_ror:4 0x124 / row_ror:8 0x128) and stages 16/32 remain shfl_xor.
//   hi/lo words move through the SAME permute per stage -> lane-coherent u64;
//   kmax on the recombined key keeps exact (max dist, tie -> lowest idx).
//   Winner index rides in the low word: no ballot/ffs/broadcast needed.
// If this FAILS (absmax ~6.55), DPP is convicted; if it PASSES, pk was guilty.
#define FPS_T 512

static __device__ __forceinline__ u64 kmax(u64 a, u64 b) { return a > b ? a : b; }

template <int CTRL>
static __device__ __forceinline__ u32 dpp_u32(u32 v) {
  return (u32)__builtin_amdgcn_update_dpp((int)v, (int)v, CTRL, 0xF, 0xF, false);
}

__global__ __launch_bounds__(FPS_T) void fps_kernel(
    const float* __restrict__ xyz,
    int* __restrict__ fps_idx, float* __restrict__ center_out) {
  #pragma clang fp contract(off)
  int b = blockIdx.x, t = threadIdx.x;
  const float* p = xyz + (size_t)b * NP * 3;
  __shared__ __align__(16) float s_xyz[NP][4];   // 64 KB, 16B rows for b128 broadcast
  __shared__ u64 s_part[2][8];
  for (int i = t; i < NP; i += FPS_T) {
    s_xyz[i][0] = p[i*3+0]; s_xyz[i][1] = p[i*3+1];
    s_xyz[i][2] = p[i*3+2]; s_xyz[i][3] = 0.f;
  }
  __syncthreads();
  const int PPT = NP / FPS_T;             // 8 points/thread
  int base = t * PPT;
  float px[PPT], py[PPT], pz[PPT], dist[PPT];
  #pragma unroll
  for (int j = 0; j < PPT; ++j) {
    px[j] = s_xyz[base+j][0]; py[j] = s_xyz[base+j][1]; pz[j] = s_xyz[base+j][2];
    dist[j] = INFINITY;
  }
  int lane = t & 63, w = t >> 6;
  u32 far = 0;
  float cx = s_xyz[0][0], cy = s_xyz[0][1], cz = s_xyz[0][2];
  for (int it = 0; it < NC; ++it) {
    if (t == 0) {
      fps_idx[b*NC + it] = (int)far;
      center_out[(size_t)(b*NC + it)*3 + 0] = cx;
      center_out[(size_t)(b*NC + it)*3 + 1] = cy;
      center_out[(size_t)(b*NC + it)*3 + 2] = cz;
    }
    // ---- scalar update (exact order: (dx*dx + dy*dy) + dz*dz, no fma) + unique keys
    u64 k[PPT];
    #pragma unroll
    for (int j = 0; j < PPT; ++j) {
      float dx = px[j] - cx, dy = py[j] - cy, dz = pz[j] - cz;
      float d = (dx*dx + dy*dy) + dz*dz;
      float nd = fminf(dist[j], d);
      dist[j] = nd;
      k[j] = ((u64)__builtin_bit_cast(u32, nd) << 32) | (u32)~(u32)(base + j);
    }
    // ---- local tree argmax (keys unique -> well-defined)
    u64 a0 = kmax(k[0], k[1]), a1 = kmax(k[2], k[3]);
    u64 a2 = kmax(k[4], k[5]), a3 = kmax(k[6], k[7]);
    u64 cur = kmax(kmax(a0, a1), kmax(a2, a3));
    // ---- u64 butterfly: DPP stages 1/2/4/8 + shfl stages 16/32
    #define DPP_STAGE64(CTRL) {                                          \
      u32 hi = (u32)(cur >> 32), lo = (u32)cur;                          \
      u32 ohi = dpp_u32<CTRL>(hi), olo = dpp_u32<CTRL>(lo);              \
      cur = kmax(cur, ((u64)ohi << 32) | olo);                           \
    }
    DPP_STAGE64(0xB1)    // quad_perm [1,0,3,2]  (xor 1)
    DPP_STAGE64(0x4E)    // quad_perm [2,3,0,1]  (xor 2)
    DPP_STAGE64(0x124)   // row_ror:4
    DPP_STAGE64(0x128)   // row_ror:8 -> 16-lane row max in all row lanes
    #undef DPP_STAGE64
    {
      u32 hi = (u32)(cur >> 32), lo = (u32)cur;
      u32 ohi = (u32)__shfl_xor((int)hi, 16), olo = (u32)__shfl_xor((int)lo, 16);
      cur = kmax(cur, ((u64)ohi << 32) | olo);
      hi = (u32)(cur >> 32); lo = (u32)cur;
      ohi = (u32)__shfl_xor((int)hi, 32); olo = (u32)__shfl_xor((int)lo, 32);
      cur = kmax(cur, ((u64)ohi << 32) | olo);
    }
    int par = it & 1;
    if (lane == 0) s_part[par][w] = cur;
    __syncthreads();
    // ---- combine 8 wave partials (broadcast reads, 3-level tree)
    u64 q0 = kmax(s_part[par][0], s_part[par][1]);
    u64 q1 = kmax(s_part[par][2], s_part[par][3]);
    u64 q2 = kmax(s_part[par][4], s_part[par][5]);
    u64 q3 = kmax(s_part[par][6], s_part[par][7]);
    u64 best = kmax(kmax(q0, q1), kmax(q2, q3));
    far = ~(u32)best;
    f32x4 c4 = *(const f32x4*)&s_xyz[far][0];   // aligned broadcast ds_read_b128
    cx = c4.x; cy = c4.y; cz = c4.z;
  }
}

// ============================================================ kNN (unchanged)
__global__ __launch_bounds__(256) void knn_kernel(
    const float* __restrict__ xyz, const float* __restrict__ sq,
    const int* __restrict__ fps_idx, int* __restrict__ grp) {
  #pragma clang fp contract(off)
  int L = blockIdx.x;
  int b = L & 7, ci = L >> 3;
  int t = threadIdx.x;
  const float* p   = xyz + (size_t)b * NP * 3;
  const float* sqb = sq + b * NP;
  __shared__ float s_d[NP];
  __shared__ float s_pval[2][4];
  __shared__ int   s_pidx[2][4];
  int center = fps_idx[b*NC + ci];
  float cx = p[center*3+0], cy = p[center*3+1], cz = p[center*3+2];
  float sqi = sqb[center];
  const int PPT = NP / 256;
  #pragma unroll
  for (int k = 0; k < PPT; ++k) {
    int j = t + k * 256;
    float dot = (cx*p[j*3+0] + cy*p[j*3+1]) + cz*p[j*3+2];
    s_d[j] = (sqi - 2.0f*dot) + sqb[j];
  }
  __syncthreads();
  int base = t * PPT;
  float lv = INFINITY; int li = 0x7fffffff;
  #pragma unroll
  for (int j = 0; j < PPT; ++j) {
    float v = s_d[base + j];
    bool bt = v < lv;
    lv = bt ? v : lv; li = bt ? (base + j) : li;
  }
  int lane = t & 63, wave = t >> 6;
  int myidx = 0;
  for (int it = 0; it < KN; ++it) {
    float bv = lv; int bi = li;
    #pragma unroll
    for (int off = 1; off < 64; off <<= 1) {
      float ov = __shfl_xor(bv, off);
      int   oi = __shfl_xor(bi, off);
      bool take = (ov < bv) || (ov == bv && oi < bi);
      bv = take ? ov : bv; bi = take ? oi : bi;
    }
    int par = it & 1;
    if (lane == 0) { s_pval[par][wave] = bv; s_pidx[par][wave] = bi; }
    __syncthreads();
    bv = s_pval[par][0]; bi = s_pidx[par][0];
    #pragma unroll
    for (int w = 1; w < 4; ++w) {
      float ov = s_pval[par][w]; int oi = s_pidx[par][w];
      bool take = (ov < bv) || (ov == bv && oi < bi);
      bv = take ? ov : bv; bi = take ? oi : bi;
    }
    if (t == it) myidx = bi;
    if ((bi >> 4) == t) {
      s_d[bi] = INFINITY;
      lv = INFINITY; li = 0x7fffffff;
      #pragma unroll
      for (int j = 0; j < PPT; ++j) {
        float v = s_d[base + j];
        bool bt = v < lv;
        lv = bt ? v : lv; li = bt ? (base + j) : li;
      }
    }
  }
  if (t < KN) grp[((size_t)(b*NC + ci))*KN + t] = myidx;
}

// ============================================================ fused MLP + maxpool (MFMA bf16, unchanged)
__global__ __launch_bounds__(256) void mlp_kernel(
    const float* __restrict__ xyz, const float* __restrict__ fea,
    const u16* __restrict__ W1f, const u16* __restrict__ W2f,
    const float* __restrict__ A1, const float* __restrict__ B1,
    const float* __restrict__ A2, const float* __restrict__ B2,
    const int* __restrict__ grp, const float* __restrict__ center_xyz,
    float* __restrict__ new_fea) {
  int L = blockIdx.x;
  int b = L & 7, pi = L >> 3;
  size_t gbase = (size_t)b * NC + pi * 2;
  int t = threadIdx.x;
  int lane = t & 63, w = t >> 6;

  __shared__ u16 sx[64][168];
  __shared__ u16 sy1[64][200];
  __shared__ int s_gidx[64];
  __shared__ float s_c[2][3];

  if (t < 64) s_gidx[t] = grp[(gbase + (t >> 5)) * KN + (t & 31)];
  if (t < 6)  s_c[t/3][t%3] = center_xyz[(gbase + t/3)*3 + (t%3)];
  __syncthreads();

  {
    int r = t >> 2, q0 = (t & 3) * 32;
    const float* src = fea + ((size_t)b*NP + s_gidx[r])*CIN + q0;
    #pragma unroll
    for (int j = 0; j < 32; j += 8) {
      float4 v0 = *(const float4*)(src + j);
      float4 v1 = *(const float4*)(src + j + 4);
      u16x8 pk;
      pk[0]=f2bf(v0.x); pk[1]=f2bf(v0.y); pk[2]=f2bf(v0.z); pk[3]=f2bf(v0.w);
      pk[4]=f2bf(v1.x); pk[5]=f2bf(v1.y); pk[6]=f2bf(v1.z); pk[7]=f2bf(v1.w);
      *(u16x8*)&sx[r][q0 + j] = pk;
    }
  }
  if (t < 64) {
    int c = t >> 5;
    const float* g = xyz + ((size_t)b*NP + s_gidx[t])*3;
    sx[t][128] = f2bf(g[0] - s_c[c][0]);
    sx[t][129] = f2bf(g[1] - s_c[c][1]);
    sx[t][130] = f2bf(g[2] - s_c[c][2]);
    #pragma unroll
    for (int j = 131; j < 160; ++j) sx[t][j] = 0;
  }
  __syncthreads();

  const f32x4 zero = {0.f, 0.f, 0.f, 0.f};

  // ---- layer 1
  {
    f32x4 acc[4][3];
    #pragma unroll
    for (int mt = 0; mt < 4; ++mt)
      #pragma unroll
      for (int nt = 0; nt < 3; ++nt) acc[mt][nt] = zero;
    #pragma unroll
    for (int kt = 0; kt < 5; ++kt) {
      s16x8 a[4];
      #pragma unroll
      for (int mt = 0; mt < 4; ++mt)
        a[mt] = *(const s16x8*)&sx[mt*16 + (lane & 15)][kt*32 + ((lane >> 4) << 3)];
      s16x8 bf[3];
      #pragma unroll
      for (int nt = 0; nt < 3; ++nt)
        bf[nt] = *(const s16x8*)&W1f[(((w*3 + nt)*5 + kt)*64 + lane) * 8];
      #pragma unroll
      for (int mt = 0; mt < 4; ++mt)
        #pragma unroll
        for (int nt = 0; nt < 3; ++nt)
          acc[mt][nt] = __builtin_amdgcn_mfma_f32_16x16x32_bf16(a[mt], bf[nt], acc[mt][nt], 0, 0, 0);
    }
    #pragma unroll
    for (int nt = 0; nt < 3; ++nt) {
      int c = w*48 + nt*16 + (lane & 15);
      float av = A1[c], bv = B1[c];
      #pragma unroll
      for (int mt = 0; mt < 4; ++mt) {
        #pragma unroll
        for (int r = 0; r < 4; ++r) {
          float v = fmaxf(fmaf(acc[mt][nt][r], av, bv), 0.f);
          sy1[mt*16 + ((lane >> 4) << 2) + r][c] = f2bf(v);
        }
      }
    }
  }
  __syncthreads();

  // ---- layer 2 + BN/ReLU + maxpool
  {
    f32x4 acc[4][4];
    #pragma unroll
    for (int mt = 0; mt < 4; ++mt)
      #pragma unroll
      for (int nt = 0; nt < 4; ++nt) acc[mt][nt] = zero;
    #pragma unroll
    for (int kt = 0; kt < 6; ++kt) {
      s16x8 a[4];
      #pragma unroll
      for (int mt = 0; mt < 4; ++mt)
        a[mt] = *(const s16x8*)&sy1[mt*16 + (lane & 15)][kt*32 + ((lane >> 4) << 3)];
      s16x8 bf[4];
      #pragma unroll
      for (int nt = 0; nt < 4; ++nt)
        bf[nt] = *(const s16x8*)&W2f[(((w*4 + nt)*6 + kt)*64 + lane) * 8];
      #pragma unroll
      for (int mt = 0; mt < 4; ++mt)
        #pragma unroll
        for (int nt = 0; nt < 4; ++nt)
          acc[mt][nt] = __builtin_amdgcn_mfma_f32_16x16x32_bf16(a[mt], bf[nt], acc[mt][nt], 0, 0, 0);
    }
    #pragma unroll
    for (int nt = 0; nt < 4; ++nt) {
      int c = w*64 + nt*16 + (lane & 15);
      float av = A2[c], bv = B2[c];
      float c0 = 0.f, c1 = 0.f;
      #pragma unroll
      for (int mt = 0; mt < 2; ++mt)
        #pragma unroll
        for (int r = 0; r < 4; ++r)
          c0 = fmaxf(c0, fmaf(acc[mt][nt][r], av, bv));
      #pragma unroll
      for (int mt = 2; mt < 4; ++mt)
        #pragma unroll
        for (int r = 0; r < 4; ++r)
          c1 = fmaxf(c1, fmaf(acc[mt][nt][r], av, bv));
      c0 = fmaxf(c0, __shfl_xor(c0, 16)); c0 = fmaxf(c0, __shfl_xor(c0, 32));
      c1 = fmaxf(c1, __shfl_xor(c1, 16)); c1 = fmaxf(c1, __shfl_xor(c1, 32));
      if (lane < 16)      new_fea[gbase*COUT + c] = c0;
      else if (lane < 32) new_fea[(gbase + 1)*COUT + c] = c1;
    }
  }
}

// ============================================================ launch
extern "C" void kernel_launch(void* const* d_in, const int* in_sizes, int n_in,
                              void* d_out, int out_size, void* d_ws, size_t ws_size,
                              hipStream_t stream) {
  const float* xyz = (const float*)d_in[0];
  const float* fea = (const float*)d_in[1];
  const float* W1  = (const float*)d_in[2];
  const float* b1  = (const float*)d_in[3];
  const float* g1  = (const float*)d_in[4];
  const float* be1 = (const float*)d_in[5];
  const float* m1  = (const float*)d_in[6];
  const float* v1  = (const float*)d_in[7];
  const float* W2  = (const float*)d_in[8];
  const float* b2  = (const float*)d_in[9];
  const float* g2  = (const float*)d_in[10];
  const float* be2 = (const float*)d_in[11];
  const float* m2  = (const float*)d_in[12];
  const float* v2  = (const float*)d_in[13];

  char* ws = (char*)d_ws;
  float* sq   = (float*)(ws + OFF_SQ);
  int*   fpsi = (int*)  (ws + OFF_FPS);
  int*   grp  = (int*)  (ws + OFF_GRP);
  float* A1   = (float*)(ws + OFF_A1);
  float* B1   = (float*)(ws + OFF_B1);
  float* A2   = (float*)(ws + OFF_A2);
  float* B2   = (float*)(ws + OFF_B2);
  u16*   W1f  = (u16*)  (ws + OFF_W1F);
  u16*   W2f  = (u16*)  (ws + OFF_W2F);

  float* out        = (float*)d_out;
  float* center_out = out;                   // [BS][NC][3]
  float* new_fea    = out + (size_t)BS*NC*3; // [BS][NC][COUT]

  prep_kernel<<<192, 256, 0, stream>>>(xyz, W1, W2, b1,g1,be1,m1,v1, b2,g2,be2,m2,v2,
                                       sq, A1,B1,A2,B2, W1f, W2f);
  fps_kernel<<<BS, FPS_T, 0, stream>>>(xyz, fpsi, center_out);
  knn_kernel<<<BS*NC, 256, 0, stream>>>(xyz, sq, fpsi, grp);
  mlp_kernel<<<BS*NC/2, 256, 0, stream>>>(xyz, fea, W1f, W2f, A1,B1,A2,B2,
                                          grp, center_out, new_fea);
}